// Round 1
// baseline (3417.371 us; speedup 1.0000x reference)
//
#include <hip/hip_runtime.h>

#define B 16
#define N 1024
#define NF 128
#define NL 3
#define AH 64
#define HC 192   // NL*AH
#define FCH 128
#define NC 10

// ---------------------------------------------------------------------------
// Kernel A: h[row][l*64+k] = x[row] . Ws[l][:,k];  f1[l][row]=h.a1[l], f2 likewise
// grid = B*N/32 blocks, 192 threads (3 waves, one per layer)
// ---------------------------------------------------------------------------
__global__ __launch_bounds__(192) void k_feat(
    const float* __restrict__ x, const float* __restrict__ Ws,
    const float* __restrict__ a1, const float* __restrict__ a2,
    float* __restrict__ h, float* __restrict__ f1, float* __restrict__ f2)
{
  __shared__ float xs[32][NF];
  const int t = threadIdx.x;
  const int n0 = blockIdx.x * 32;

  // stage 32 rows of x (32*128 floats) as float4
  for (int p = t; p < 32 * NF / 4; p += 192) {
    const int row = p >> 5, c4 = p & 31;           // 32 float4 per row
    *(float4*)&xs[row][c4 * 4] =
        *(const float4*)&x[(size_t)(n0 + row) * NF + c4 * 4];
  }
  __syncthreads();

  const int l = t >> 6, k = t & 63;
  const float* w = Ws + (size_t)l * NF * AH + k;   // stride AH per f

  float acc[32];
  #pragma unroll
  for (int ii = 0; ii < 32; ++ii) acc[ii] = 0.f;

  for (int f0 = 0; f0 < NF; f0 += 4) {
    const float w0 = w[(f0 + 0) * AH], w1 = w[(f0 + 1) * AH];
    const float w2 = w[(f0 + 2) * AH], w3 = w[(f0 + 3) * AH];
    #pragma unroll
    for (int ii = 0; ii < 32; ++ii) {
      const float4 xv = *(const float4*)&xs[ii][f0];
      acc[ii] += xv.x * w0 + xv.y * w1 + xv.z * w2 + xv.w * w3;
    }
  }

  const float a1v = a1[t], a2v = a2[t];
  #pragma unroll
  for (int ii = 0; ii < 32; ++ii) {
    h[(size_t)(n0 + ii) * HC + t] = acc[ii];
    float p1 = acc[ii] * a1v, p2 = acc[ii] * a2v;
    #pragma unroll
    for (int off = 32; off; off >>= 1) {
      p1 += __shfl_down(p1, off);
      p2 += __shfl_down(p2, off);
    }
    if (k == 0) {
      f1[(size_t)l * (B * N) + n0 + ii] = p1;
      f2[(size_t)l * (B * N) + n0 + ii] = p2;
    }
  }
}

// ---------------------------------------------------------------------------
// Kernel M: m[l*B+b] = max_n f2[l][b][n]   (unmasked max -> valid softmax shift)
// ---------------------------------------------------------------------------
__global__ __launch_bounds__(256) void k_max(const float* __restrict__ f2,
                                             float* __restrict__ m)
{
  const int lb = blockIdx.x;                 // 0..47 = l*B+b
  const float* p = f2 + (size_t)lb * N;
  float v = -1e30f;
  for (int i = threadIdx.x; i < N; i += 256) v = fmaxf(v, p[i]);
  #pragma unroll
  for (int off = 32; off; off >>= 1) v = fmaxf(v, __shfl_down(v, off));
  __shared__ float wsred[4];
  if ((threadIdx.x & 63) == 0) wsred[threadIdx.x >> 6] = v;
  __syncthreads();
  if (threadIdx.x == 0)
    m[lb] = fmaxf(fmaxf(wsred[0], wsred[1]), fmaxf(wsred[2], wsred[3]));
}

// ---------------------------------------------------------------------------
// Kernel B: fused 3-layer masked-softmax attention + att@h + relu
// grid = B * (N/32) blocks, 192 threads. TI=32 i-rows, TJ=32 j-cols per step.
// ---------------------------------------------------------------------------
#define TI 32
#define TJ 32

__global__ __launch_bounds__(192) void k_att(
    const float* __restrict__ adj, const float* __restrict__ h,
    const float* __restrict__ f1, const float* __restrict__ f2,
    const float* __restrict__ m, float* __restrict__ gout)
{
  const int blk = blockIdx.x;
  const int b = blk >> 5;                 // /(N/TI)=32
  const int i0 = (blk & 31) * TI;
  const int t = threadIdx.x;              // 0..191

  __shared__ float h_lds[TJ][HC];         // 24 KB
  __shared__ float w_lds[NL][TI][TJ];     // 12 KB
  __shared__ float f2_lds[NL][TJ];
  __shared__ float f1_lds[NL][TI];
  __shared__ float s_lds[NL][TI];
  __shared__ float sumw[NL][TI];

  if (t < 96) {
    const int l = t >> 5, ii = t & 31;
    const float f1v = f1[(size_t)l * (B * N) + b * N + i0 + ii];
    float sv = f1v + m[l * B + b];
    sv = sv > 0.f ? sv : 0.2f * sv;       // leaky(f1_i + max_j f2_j) >= every masked e
    f1_lds[l][ii] = f1v;
    s_lds[l][ii] = sv;
    sumw[l][ii] = 0.f;
  }

  float acc[TI];
  #pragma unroll
  for (int ii = 0; ii < TI; ++ii) acc[ii] = 0.f;

  const int l_t = t >> 6;                 // layer owned in accumulate phase
  const int r4 = t / 48, c4 = t % 48;     // h staging coords (48 float4 per row)
  __syncthreads();

  for (int j0 = 0; j0 < N; j0 += TJ) {
    // ---- phase 1: stage h chunk [TJ][192] + f2 chunk ----
    #pragma unroll
    for (int it = 0; it < 8; ++it) {
      const int row = it * 4 + r4;
      *(float4*)&h_lds[row][c4 * 4] =
          *(const float4*)&h[(size_t)(b * N + j0 + row) * HC + c4 * 4];
    }
    if (t < 96) {
      const int l = t >> 5, jj = t & 31;
      f2_lds[l][jj] = f2[(size_t)l * (B * N) + b * N + j0 + jj];
    }
    __syncthreads();

    // ---- phase 2: attention weights for 32x32 tile, all 3 layers ----
    for (int p = t; p < TI * TJ; p += 192) {
      const int ii = p >> 5, jj = p & 31;
      const float a = adj[(size_t)(b * N + i0 + ii) * N + j0 + jj];
      #pragma unroll
      for (int l = 0; l < NL; ++l) {
        float e = f1_lds[l][ii] + f2_lds[l][jj];
        e = e > 0.f ? e : 0.2f * e;
        w_lds[l][ii][jj] = (a > 0.f) ? __expf(e - s_lds[l][ii]) : 0.f;
      }
    }
    __syncthreads();

    // ---- phase 3: acc[ii] += w[l_t][ii][:] . h_lds[:][t] ----
    #pragma unroll
    for (int jj0 = 0; jj0 < TJ; jj0 += 4) {
      const float hv0 = h_lds[jj0 + 0][t];
      const float hv1 = h_lds[jj0 + 1][t];
      const float hv2 = h_lds[jj0 + 2][t];
      const float hv3 = h_lds[jj0 + 3][t];
      #pragma unroll
      for (int ii = 0; ii < TI; ++ii) {
        const float4 w4 = *(const float4*)&w_lds[l_t][ii][jj0];
        acc[ii] += w4.x * hv0 + w4.y * hv1 + w4.z * hv2 + w4.w * hv3;
      }
    }
    if (t < 96) {                          // sum of weights for the softmax denom
      const int l = t >> 5, ii = t & 31;
      float s = 0.f;
      #pragma unroll
      for (int jj = 0; jj < TJ; ++jj) s += w_lds[l][ii][jj];
      sumw[l][ii] += s;
    }
    __syncthreads();
  }

  // ---- epilogue: divide by denom, relu, store ----
  #pragma unroll
  for (int ii = 0; ii < TI; ++ii) {
    const float denom = fmaxf(sumw[l_t][ii], 1e-37f);
    float v = acc[ii] / denom;
    gout[(size_t)(b * N + i0 + ii) * HC + t] = v > 0.f ? v : 0.f;
  }
}

// ---------------------------------------------------------------------------
// Kernel C: mean-pool over nodes + FC1(relu) + FC2 + softmax
// grid = B blocks, 192 threads
// ---------------------------------------------------------------------------
__global__ __launch_bounds__(192) void k_head(
    const float* __restrict__ gout, const float* __restrict__ W1,
    const float* __restrict__ b1, const float* __restrict__ W2,
    const float* __restrict__ b2, float* __restrict__ out)
{
  const int b = blockIdx.x, t = threadIdx.x;
  __shared__ float pooled[HC];
  __shared__ float z[FCH];
  __shared__ float logits[NC];

  float s0 = 0.f, s1 = 0.f, s2 = 0.f, s3 = 0.f;
  const float* base = gout + (size_t)b * N * HC + t;
  for (int n = 0; n < N; n += 4) {
    s0 += base[(size_t)(n + 0) * HC];
    s1 += base[(size_t)(n + 1) * HC];
    s2 += base[(size_t)(n + 2) * HC];
    s3 += base[(size_t)(n + 3) * HC];
  }
  pooled[t] = (s0 + s1 + s2 + s3) * (1.f / (float)N);
  __syncthreads();

  if (t < FCH) {
    float a = b1[t];
    #pragma unroll 4
    for (int f = 0; f < HC; ++f) a += pooled[f] * W1[(size_t)f * FCH + t];
    z[t] = a > 0.f ? a : 0.f;
  }
  __syncthreads();

  if (t < NC) {
    float a = b2[t];
    #pragma unroll 4
    for (int f = 0; f < FCH; ++f) a += z[f] * W2[(size_t)f * NC + t];
    logits[t] = a;
  }
  __syncthreads();

  if (t == 0) {
    float mx = logits[0];
    for (int c = 1; c < NC; ++c) mx = fmaxf(mx, logits[c]);
    float e[NC], sum = 0.f;
    for (int c = 0; c < NC; ++c) { e[c] = __expf(logits[c] - mx); sum += e[c]; }
    const float inv = 1.f / sum;
    for (int c = 0; c < NC; ++c) out[b * NC + c] = e[c] * inv;
  }
}

// ---------------------------------------------------------------------------
extern "C" void kernel_launch(void* const* d_in, const int* in_sizes, int n_in,
                              void* d_out, int out_size, void* d_ws, size_t ws_size,
                              hipStream_t stream)
{
  const float* x   = (const float*)d_in[0];
  const float* adj = (const float*)d_in[1];
  const float* Ws  = (const float*)d_in[2];
  const float* a1  = (const float*)d_in[3];
  const float* a2  = (const float*)d_in[4];
  const float* W1  = (const float*)d_in[5];
  const float* b1  = (const float*)d_in[6];
  const float* W2  = (const float*)d_in[7];
  const float* b2  = (const float*)d_in[8];
  float* out = (float*)d_out;

  float* ws   = (float*)d_ws;
  float* h    = ws;                                   // B*N*HC
  float* f1   = h  + (size_t)B * N * HC;              // NL*B*N
  float* f2   = f1 + (size_t)NL * B * N;              // NL*B*N
  float* mbuf = f2 + (size_t)NL * B * N;              // 64 (padded)
  float* gout = mbuf + 64;                            // B*N*HC

  k_feat<<<B * N / 32, 192, 0, stream>>>(x, Ws, a1, a2, h, f1, f2);
  k_max <<<NL * B,     256, 0, stream>>>(f2, mbuf);
  k_att <<<B * (N / TI), 192, 0, stream>>>(adj, h, f1, f2, mbuf, gout);
  k_head<<<B,          192, 0, stream>>>(gout, W1, b1, W2, b2, out);
}

// Round 2
// 139.646 us; speedup vs baseline: 24.4716x; 24.4716x over previous
//
#include <hip/hip_runtime.h>

#define B 16
#define N 1024
#define NF 128
#define NL 3
#define AH 64
#define HC 192   // NL*AH
#define FCH 128
#define NC 10

typedef __attribute__((ext_vector_type(8))) short bf16x8;
typedef __attribute__((ext_vector_type(4))) float f32x4;

static __device__ __forceinline__ unsigned short f2bf(float f) {
  unsigned int x = __builtin_bit_cast(unsigned int, f);
  unsigned int r = (x + 0x7fffu + ((x >> 16) & 1u)) >> 16;   // RNE
  return (unsigned short)r;
}

// ---------------------------------------------------------------------------
// Kernel A: h_t[b][c][n] = bf16( x[b,n,:] . Ws[l][:,c&63] );  f1/f2 row dots.
// grid = B*N/32 blocks, 192 threads (one thread per output channel c).
// ---------------------------------------------------------------------------
__global__ __launch_bounds__(192) void k_feat(
    const float* __restrict__ x, const float* __restrict__ Ws,
    const float* __restrict__ a1, const float* __restrict__ a2,
    unsigned short* __restrict__ h_t, float* __restrict__ f1, float* __restrict__ f2)
{
  __shared__ float xs[32][NF];
  const int t = threadIdx.x;
  const int n0 = blockIdx.x * 32;          // flat row over B*N
  const int gb = n0 >> 10, nl0 = n0 & 1023;

  for (int p = t; p < 32 * NF / 4; p += 192) {
    const int row = p >> 5, c4 = p & 31;
    *(float4*)&xs[row][c4 * 4] =
        *(const float4*)&x[(size_t)(n0 + row) * NF + c4 * 4];
  }
  __syncthreads();

  const int l = t >> 6, k = t & 63;
  const float* w = Ws + (size_t)l * NF * AH + k;   // stride AH per feature

  float acc[32];
  #pragma unroll
  for (int ii = 0; ii < 32; ++ii) acc[ii] = 0.f;

  for (int f0 = 0; f0 < NF; f0 += 4) {
    const float w0 = w[(f0 + 0) * AH], w1 = w[(f0 + 1) * AH];
    const float w2 = w[(f0 + 2) * AH], w3 = w[(f0 + 3) * AH];
    #pragma unroll
    for (int ii = 0; ii < 32; ++ii) {
      const float4 xv = *(const float4*)&xs[ii][f0];
      acc[ii] += xv.x * w0 + xv.y * w1 + xv.z * w2 + xv.w * w3;
    }
  }

  // h_t store: 32 consecutive bf16 per thread (64B), 16B-aligned
  unsigned short* dst = h_t + (((size_t)(gb * HC + t)) << 10) + nl0;
  #pragma unroll
  for (int g8 = 0; g8 < 4; ++g8) {
    uint4 v;
    unsigned int* vp = (unsigned int*)&v;
    #pragma unroll
    for (int j = 0; j < 4; ++j) {
      const int ii = g8 * 8 + j * 2;
      vp[j] = (unsigned int)f2bf(acc[ii]) | ((unsigned int)f2bf(acc[ii + 1]) << 16);
    }
    *(uint4*)&dst[g8 * 8] = v;
  }

  const float a1v = a1[t], a2v = a2[t];
  #pragma unroll
  for (int ii = 0; ii < 32; ++ii) {
    float p1 = acc[ii] * a1v, p2 = acc[ii] * a2v;
    #pragma unroll
    for (int off = 32; off; off >>= 1) {
      p1 += __shfl_down(p1, off);
      p2 += __shfl_down(p2, off);
    }
    if (k == 0) {
      f1[(size_t)l * (B * N) + n0 + ii] = p1;
      f2[(size_t)l * (B * N) + n0 + ii] = p2;
    }
  }
}

// ---------------------------------------------------------------------------
// Kernel M: m[l*B+b] = max_n f2[l][b][n]  (unmasked max = valid softmax shift)
// ---------------------------------------------------------------------------
__global__ __launch_bounds__(256) void k_max(const float* __restrict__ f2,
                                             float* __restrict__ m)
{
  const int lb = blockIdx.x;
  const float* p = f2 + (size_t)lb * N;
  float v = -1e30f;
  for (int i = threadIdx.x; i < N; i += 256) v = fmaxf(v, p[i]);
  #pragma unroll
  for (int off = 32; off; off >>= 1) v = fmaxf(v, __shfl_down(v, off));
  __shared__ float wsred[4];
  if ((threadIdx.x & 63) == 0) wsred[threadIdx.x >> 6] = v;
  __syncthreads();
  if (threadIdx.x == 0)
    m[lb] = fmaxf(fmaxf(wsred[0], wsred[1]), fmaxf(wsred[2], wsred[3]));
}

// ---------------------------------------------------------------------------
// Kernel B: fused 3-layer GAT attention, MFMA PV, fused relu+pool.
// grid = B*(N/64) = 256 blocks, 384 threads = 6 waves.
// wave (l, kk): layer l, K-half kk; computes P^l[64 rows][32 k] in registers,
// B-frags straight from global h_t, 16 MFMAs per j-step.
// ---------------------------------------------------------------------------
__global__ __launch_bounds__(384) void k_att(
    const float* __restrict__ adj, const unsigned short* __restrict__ h_t,
    const float* __restrict__ f1, const float* __restrict__ f2,
    const float* __restrict__ m, float* __restrict__ pooled)
{
  const int blk = blockIdx.x;
  const int b = blk >> 4;
  const int i0 = (blk & 15) * 64;
  const int t = threadIdx.x;
  const int w = t >> 6, lane = t & 63;
  const int l = w >> 1, kk = w & 1;
  const int lr = lane & 15, lg = lane >> 4;

  __shared__ float f2all[NL][N];        // 12 KB
  __shared__ float f1s[NL][64];         // raw f1 per row
  __shared__ float ssh[NL][64];         // shift s per row
  __shared__ float sumw[NL][64];        // softmax denominators
  __shared__ float adjf[64][68];        // adj tile, +4 pad (17.4 KB)
  __shared__ float red[NL][64][64];     // 48 KB epilogue kk-reduction

  for (int q = t; q < NL * N; q += 384) {
    const int li = q >> 10, jj = q & 1023;
    f2all[li][jj] = f2[(size_t)li * (B * N) + b * N + jj];
  }
  if (t < 192) {
    const int li = t >> 6, ii = t & 63;
    const float f1v = f1[(size_t)li * (B * N) + b * N + i0 + ii];
    float sv = f1v + m[li * B + b];
    sv = sv > 0.f ? sv : 0.2f * sv;
    f1s[li][ii] = f1v;
    ssh[li][ii] = sv;
    sumw[li][ii] = 0.f;
  }

  // adj prologue: prefetch tile j0=0 into registers (T14 pattern)
  float4 areg[3];
  #pragma unroll
  for (int s = 0; s < 3; ++s) {
    const int q = t + s * 384;
    if (q < 1024)
      areg[s] = *(const float4*)&adj[(size_t)(b * N + i0 + (q >> 4)) * N + (q & 15) * 4];
  }
  __syncthreads();

  // per-row loop invariants for this wave's layer
  float f1r[4], sr[4];
  #pragma unroll
  for (int mm = 0; mm < 4; ++mm) {
    f1r[mm] = f1s[l][lr + 16 * mm];
    sr[mm]  = ssh[l][lr + 16 * mm];
  }

  f32x4 acc[4][4];
  #pragma unroll
  for (int mm = 0; mm < 4; ++mm)
    #pragma unroll
    for (int n = 0; n < 4; ++n)
      acc[mm][n] = (f32x4){0.f, 0.f, 0.f, 0.f};
  float rs[4] = {0.f, 0.f, 0.f, 0.f};

  const int kbase = kk * 32 + lg * 8;   // k offset within 64-j tile

  for (int j0 = 0; j0 < N; j0 += 64) {
    __syncthreads();                    // previous step's adjf reads done
    #pragma unroll
    for (int s = 0; s < 3; ++s) {
      const int q = t + s * 384;
      if (q < 1024) *(float4*)&adjf[q >> 4][(q & 15) * 4] = areg[s];
    }
    if (j0 + 64 < N) {                  // prefetch next tile; in flight over compute
      #pragma unroll
      for (int s = 0; s < 3; ++s) {
        const int q = t + s * 384;
        if (q < 1024)
          areg[s] = *(const float4*)&adj[(size_t)(b * N + i0 + (q >> 4)) * N + (j0 + 64) + (q & 15) * 4];
      }
    }
    __syncthreads();                    // adjf ready

    // B-fragments straight from global h_t (L2-resident), issue early
    bf16x8 bfr[4];
    #pragma unroll
    for (int n = 0; n < 4; ++n) {
      const int col = l * 64 + n * 16 + lr;
      bfr[n] = *(const bf16x8*)&h_t[(((size_t)(b * HC + col)) << 10) + j0 + kbase];
    }

    // f2 values for this lane's 8 k (wave-uniform per lg group: broadcast)
    float fv[8];
    {
      const float* f2p = &f2all[l][j0 + kbase];
      #pragma unroll
      for (int e = 0; e < 8; ++e) fv[e] = f2p[e];
    }

    // A-fragments in registers: P = exp(leaky(f1+f2) - s), masked
    bf16x8 afr[4];
    #pragma unroll
    for (int mm = 0; mm < 4; ++mm) {
      const int row = lr + 16 * mm;
      const float4 fm0 = *(const float4*)&adjf[row][kbase];
      const float4 fm1 = *(const float4*)&adjf[row][kbase + 4];
      const float mk[8] = {fm0.x, fm0.y, fm0.z, fm0.w, fm1.x, fm1.y, fm1.z, fm1.w};
      float s8 = 0.f;
      bf16x8 av;
      #pragma unroll
      for (int e = 0; e < 8; ++e) {
        const float tt = f1r[mm] + fv[e];
        const float el = fmaxf(tt, 0.f) + 0.2f * fminf(tt, 0.f);
        float pv = __expf(el - sr[mm]);
        pv = (mk[e] > 0.f) ? pv : 0.f;
        s8 += pv;
        av[e] = (short)f2bf(pv);
      }
      rs[mm] += s8;
      afr[mm] = av;
    }

    #pragma unroll
    for (int n = 0; n < 4; ++n)
      #pragma unroll
      for (int mm = 0; mm < 4; ++mm)
        acc[mm][n] = __builtin_amdgcn_mfma_f32_16x16x32_bf16(afr[mm], bfr[n], acc[mm][n], 0, 0, 0);
  }

  // ---- epilogue ----
  // softmax denominators: reduce rs across the 4 lane-groups, add both kk halves
  #pragma unroll
  for (int mm = 0; mm < 4; ++mm) {
    float v = rs[mm];
    v += __shfl_xor(v, 16);
    v += __shfl_xor(v, 32);
    if (lg == 0) atomicAdd(&sumw[l][lr + 16 * mm], v);
  }
  // kk=1 waves dump partial acc to LDS
  if (kk == 1) {
    #pragma unroll
    for (int mm = 0; mm < 4; ++mm)
      #pragma unroll
      for (int n = 0; n < 4; ++n)
        #pragma unroll
        for (int r = 0; r < 4; ++r)
          red[l][mm * 16 + lg * 4 + r][n * 16 + lr] = acc[mm][n][r];
  }
  __syncthreads();
  if (kk == 0) {
    #pragma unroll
    for (int n = 0; n < 4; ++n) {
      float csum = 0.f;
      #pragma unroll
      for (int mm = 0; mm < 4; ++mm) {
        #pragma unroll
        for (int r = 0; r < 4; ++r) {
          const int row = mm * 16 + lg * 4 + r;
          float v = acc[mm][n][r] + red[l][row][n * 16 + lr];
          v /= fmaxf(sumw[l][row], 1e-37f);
          csum += fmaxf(v, 0.f);
        }
      }
      csum += __shfl_xor(csum, 16);
      csum += __shfl_xor(csum, 32);
      if (lg == 0) atomicAdd(&pooled[b * HC + l * 64 + n * 16 + lr], csum);
    }
  }
}

// ---------------------------------------------------------------------------
// Kernel C: mean (pooled sums / N) + FC1(relu) + FC2 + softmax.  grid = B.
// ---------------------------------------------------------------------------
__global__ __launch_bounds__(192) void k_head(
    const float* __restrict__ pooled_sums, const float* __restrict__ W1,
    const float* __restrict__ b1, const float* __restrict__ W2,
    const float* __restrict__ b2, float* __restrict__ out)
{
  const int b = blockIdx.x, t = threadIdx.x;
  __shared__ float pooled[HC];
  __shared__ float z[FCH];
  __shared__ float logits[NC];

  if (t < HC) pooled[t] = pooled_sums[b * HC + t] * (1.f / (float)N);
  __syncthreads();

  if (t < FCH) {
    float a = b1[t];
    #pragma unroll 4
    for (int f = 0; f < HC; ++f) a += pooled[f] * W1[(size_t)f * FCH + t];
    z[t] = a > 0.f ? a : 0.f;
  }
  __syncthreads();

  if (t < NC) {
    float a = b2[t];
    #pragma unroll 4
    for (int f = 0; f < FCH; ++f) a += z[f] * W2[(size_t)f * NC + t];
    logits[t] = a;
  }
  __syncthreads();

  if (t == 0) {
    float mx = logits[0];
    for (int c = 1; c < NC; ++c) mx = fmaxf(mx, logits[c]);
    float e[NC], sum = 0.f;
    for (int c = 0; c < NC; ++c) { e[c] = __expf(logits[c] - mx); sum += e[c]; }
    const float inv = 1.f / sum;
    for (int c = 0; c < NC; ++c) out[b * NC + c] = e[c] * inv;
  }
}

// ---------------------------------------------------------------------------
extern "C" void kernel_launch(void* const* d_in, const int* in_sizes, int n_in,
                              void* d_out, int out_size, void* d_ws, size_t ws_size,
                              hipStream_t stream)
{
  const float* x   = (const float*)d_in[0];
  const float* adj = (const float*)d_in[1];
  const float* Ws  = (const float*)d_in[2];
  const float* a1  = (const float*)d_in[3];
  const float* a2  = (const float*)d_in[4];
  const float* W1  = (const float*)d_in[5];
  const float* b1  = (const float*)d_in[6];
  const float* W2  = (const float*)d_in[7];
  const float* b2  = (const float*)d_in[8];
  float* out = (float*)d_out;

  unsigned short* h_t = (unsigned short*)d_ws;                    // B*HC*N bf16
  float* f1   = (float*)(h_t + (size_t)B * HC * N);               // NL*B*N
  float* f2   = f1 + (size_t)NL * B * N;                          // NL*B*N
  float* mbuf = f2 + (size_t)NL * B * N;                          // 64
  float* pooled = mbuf + 64;                                      // B*HC

  hipMemsetAsync(pooled, 0, (size_t)B * HC * sizeof(float), stream);
  k_feat<<<B * N / 32, 192, 0, stream>>>(x, Ws, a1, a2, h_t, f1, f2);
  k_max <<<NL * B,     256, 0, stream>>>(f2, mbuf);
  k_att <<<B * (N / 64), 384, 0, stream>>>(adj, h_t, f1, f2, mbuf, pooled);
  k_head<<<B,          192, 0, stream>>>(pooled, W1, b1, W2, b2, out);
}